// Round 6
// baseline (127.017 us; speedup 1.0000x reference)
//
#include <hip/hip_runtime.h>
#include <math.h>

#define BB 4
#define NN 1024
#define HH 8
#define NROW (BB*NN)  // 4096

typedef short s8v __attribute__((ext_vector_type(8)));
typedef float f4v __attribute__((ext_vector_type(4)));

__device__ __forceinline__ float lrelu(float x) { return fmaxf(x, 0.2f * x); }
__device__ __forceinline__ short bf16rne(float f) {
    unsigned u = __float_as_uint(f);
    u += 0x7FFF + ((u >> 16) & 1u);
    return (short)(u >> 16);
}

// ---------------------------------------------------------------------------
// K1: g = h@W + fused e_i/e_j. DE-SPILLED (r6): acc[8] -> named c0..c7.
// ---------------------------------------------------------------------------
__global__ __launch_bounds__(256) void k_gemm_ei(const float* __restrict__ hm,
                                                 const float* __restrict__ W,
                                                 const float* __restrict__ aw,
                                                 float* __restrict__ g,
                                                 float* __restrict__ e_i,
                                                 float* __restrict__ e_j,
                                                 float* __restrict__ e_jt) {
    __shared__ __align__(16) float hs[8][256];
    __shared__ float aws[64];
    const int row0 = blockIdx.x * 8;
    const int t = threadIdx.x;
    if (t < 64) aws[t] = aw[t];
    const float4* h4 = (const float4*)(hm + row0 * 256);
    float4* hs4 = (float4*)&hs[0][0];
    hs4[t] = h4[t];
    hs4[t + 256] = h4[t + 256];
    __syncthreads();

    float c0 = 0.f, c1 = 0.f, c2 = 0.f, c3 = 0.f, c4 = 0.f, c5 = 0.f, c6 = 0.f, c7 = 0.f;
    for (int k4 = 0; k4 < 64; ++k4) {
        const float w0 = W[(4 * k4 + 0) * 256 + t];
        const float w1 = W[(4 * k4 + 1) * 256 + t];
        const float w2 = W[(4 * k4 + 2) * 256 + t];
        const float w3 = W[(4 * k4 + 3) * 256 + t];
#define ROW(r)                                                        \
        {                                                             \
            const float4 hv = *(const float4*)&hs[r][4 * k4];         \
            c##r = fmaf(hv.x, w0, c##r);                              \
            c##r = fmaf(hv.y, w1, c##r);                              \
            c##r = fmaf(hv.z, w2, c##r);                              \
            c##r = fmaf(hv.w, w3, c##r);                              \
        }
        ROW(0) ROW(1) ROW(2) ROW(3) ROW(4) ROW(5) ROW(6) ROW(7)
#undef ROW
    }
    const int d = t & 31, hh = t >> 5;
    const int b = row0 >> 10;
#define EPI(r)                                                                  \
    {                                                                           \
        g[(row0 + r) * 256 + t] = c##r;                                         \
        float vi = c##r * aws[d];                                               \
        float vj = c##r * aws[32 + d];                                          \
        for (int mm = 1; mm < 32; mm <<= 1) {                                   \
            vi += __shfl_xor(vi, mm);                                           \
            vj += __shfl_xor(vj, mm);                                           \
        }                                                                       \
        if (d == 0) {                                                           \
            e_i[(row0 + r) * 8 + hh] = vi;                                      \
            e_j[(row0 + r) * 8 + hh] = vj;                                      \
            e_jt[(size_t)(b * 8 + hh) * NN + ((row0 + r) & (NN - 1))] = vj;     \
        }                                                                       \
    }
    EPI(0) EPI(1) EPI(2) EPI(3) EPI(4) EPI(5) EPI(6) EPI(7)
#undef EPI
}

// ---------------------------------------------------------------------------
// K2: column-sum partials. DE-SPILLED (r6): sacc[8]/ejv[8] -> named s0..s7,
// e0..e7; eis reads as f4v broadcast pairs.
// ---------------------------------------------------------------------------
__global__ __launch_bounds__(256) void k_s(const float* __restrict__ adj,
                                           const float* __restrict__ e_i,
                                           const float* __restrict__ e_j,
                                           float* __restrict__ ps) {
    __shared__ __align__(16) float eis[128 * 8];
    __shared__ float ejs[8][64];
    __shared__ float sp[4][8][64];
    const int bx = blockIdx.x;
    const int b = bx >> 7, jc = (bx >> 3) & 15, ic = bx & 7;
    const int j0 = jc * 64, i0 = ic * 128;
    const int t = threadIdx.x;

    ((float4*)eis)[t] = ((const float4*)(e_i + (b * NN + i0) * 8))[t];
    if (t < 128) {
        const float4 v = ((const float4*)(e_j + (b * NN + j0) * 8))[t];
        const int base = t * 4;
        ejs[(base + 0) & 7][(base + 0) >> 3] = v.x;
        ejs[(base + 1) & 7][(base + 1) >> 3] = v.y;
        ejs[(base + 2) & 7][(base + 2) >> 3] = v.z;
        ejs[(base + 3) & 7][(base + 3) >> 3] = v.w;
    }
    __syncthreads();

    const int ii = t >> 6, jj = t & 63;
    const float e0 = ejs[0][jj], e1 = ejs[1][jj], e2 = ejs[2][jj], e3 = ejs[3][jj];
    const float e4 = ejs[4][jj], e5 = ejs[5][jj], e6 = ejs[6][jj], e7 = ejs[7][jj];
    float s0 = 0.f, s1 = 0.f, s2 = 0.f, s3 = 0.f, s4 = 0.f, s5 = 0.f, s6 = 0.f, s7 = 0.f;
    const float* adjp = adj + (size_t)b * NN * NN + j0 + jj;
    for (int i = ii; i < 128; i += 4) {
        const float a = adjp[(size_t)(i0 + i) * NN];
        const f4v eA = *(const f4v*)&eis[i * 8];
        const f4v eB = *(const f4v*)&eis[i * 8 + 4];
        s0 = fmaf(a, __expf(lrelu(eA[0] + e0)), s0);
        s1 = fmaf(a, __expf(lrelu(eA[1] + e1)), s1);
        s2 = fmaf(a, __expf(lrelu(eA[2] + e2)), s2);
        s3 = fmaf(a, __expf(lrelu(eA[3] + e3)), s3);
        s4 = fmaf(a, __expf(lrelu(eB[0] + e4)), s4);
        s5 = fmaf(a, __expf(lrelu(eB[1] + e5)), s5);
        s6 = fmaf(a, __expf(lrelu(eB[2] + e6)), s6);
        s7 = fmaf(a, __expf(lrelu(eB[3] + e7)), s7);
    }
    sp[ii][0][jj] = s0; sp[ii][1][jj] = s1; sp[ii][2][jj] = s2; sp[ii][3][jj] = s3;
    sp[ii][4][jj] = s4; sp[ii][5][jj] = s5; sp[ii][6][jj] = s6; sp[ii][7][jj] = s7;
    __syncthreads();
#pragma unroll
    for (int k = 0; k < 2; ++k) {
        const int idx = t * 2 + k;
        const int jjo = idx >> 3, h = idx & 7;
        const float s = sp[0][h][jjo] + sp[1][h][jjo] + sp[2][h][jjo] + sp[3][h][jjo];
        ps[ic * (NROW * 8) + (b * NN + j0 + jjo) * 8 + h] = s;
    }
}

// ---------------------------------------------------------------------------
// K3: rs = 1/sum(ps); Gt = bf16(g*rs) pre-tiled. DE-SPILLED (r6): v16[16] ->
// direct packing into named uint4 components.
// ---------------------------------------------------------------------------
__global__ __launch_bounds__(256) void k_prep(const float* __restrict__ ps,
                                              const float* __restrict__ g,
                                              short* __restrict__ Gt) {
    __shared__ float rss[16][8];
    const int bx = blockIdx.x;
    const int b = bx >> 6, j0 = (bx & 63) * 16;
    const int t = threadIdx.x;
    if (t < 128) {
        const int jj = t >> 3, h = t & 7;
        float s = 0.f;
#pragma unroll
        for (int ic = 0; ic < 8; ++ic)
            s += ps[ic * (NROW * 8) + (b * NN + j0 + jj) * 8 + h];
        rss[jj][h] = 1.0f / s;
    }
    __syncthreads();
    const int h = t >> 5, d = t & 31;
    uint4 w0, w1;
#define PK(dst, r0, r1)                                                          \
    {                                                                            \
        const float va = g[(size_t)(b * NN + j0 + r0) * 256 + t] * rss[r0][h];   \
        const float vb = g[(size_t)(b * NN + j0 + r1) * 256 + t] * rss[r1][h];   \
        dst = (unsigned)(unsigned short)bf16rne(va) |                            \
              ((unsigned)(unsigned short)bf16rne(vb) << 16);                     \
    }
    PK(w0.x, 0, 1) PK(w0.y, 2, 3) PK(w0.z, 4, 5) PK(w0.w, 6, 7)
    PK(w1.x, 8, 9) PK(w1.y, 10, 11) PK(w1.z, 12, 13) PK(w1.w, 14, 15)
#undef PK
    const int jt = j0 >> 5, jj0 = j0 & 31;
    short* dst = Gt + ((size_t)((b * 8 + h) * 32 + jt)) * 1024 + d * 32 + jj0;
    *(uint4*)dst = w0;
    *(uint4*)(dst + 8) = w1;
}

// ---------------------------------------------------------------------------
// K4: MFMA contraction, named-reg only (r5 fix) + software pipeline (r6):
// next super-step's Gt/adj/ej prefetched into named regs during compute,
// rotated via named copies after compute (forces vmcnt wait post-compute).
// ---------------------------------------------------------------------------
__global__ __launch_bounds__(256) void k_out_mfma(const float* __restrict__ adj,
                                                  const short* __restrict__ Gt,
                                                  const float* __restrict__ e_i,
                                                  const float* __restrict__ e_jt,
                                                  float* __restrict__ out) {
    __shared__ short gts[4][4][32][40];  // 40KB: [h-local][jt-local][d][jj+pad]
    __shared__ float ejt[4][128];        // 2KB
    const int bx = blockIdx.x;
    const int hs = bx >> 8, b = (bx >> 6) & 3, i0 = (bx & 63) * 16;
    const int t = threadIdx.x;
    const int wave = t >> 6, lane = t & 63;
    const int m = lane & 15, q = lane >> 4;
    const int h = hs * 4 + wave;  // this wave's head

    const float ei = e_i[(size_t)(b * NN + i0 + m) * 8 + h];
    f4v acc0 = {0.f, 0.f, 0.f, 0.f}, acc1 = {0.f, 0.f, 0.f, 0.f};

    const float* adjrow = adj + (size_t)b * NN * NN + (size_t)(i0 + m) * NN;
    const float4* gtg4 = (const float4*)Gt;  // 8 shorts per float4
    const float4* ejt4 = (const float4*)(e_jt + (size_t)b * 8 * NN);

#define LGD(k, sv, dst)                                                          \
    {                                                                            \
        const int u = t + 256 * (k);                                             \
        dst = gtg4[(size_t)(b * 8 + hs * 4 + (u >> 9)) * 4096 + (sv) * 512 +     \
                   (u & 511)];                                                   \
    }
#define LAD(sv, lt, half, dst)                                                   \
    dst = *(const f4v*)&adjrow[(sv) * 128 + (lt) * 32 + q * 8 + (half) * 4];

    float4 g0, g1, g2, g3, g4, g5, g6, g7;
    f4v a0, a1, a2, a3, a4, a5, a6, a7;
    float4 ev = make_float4(0.f, 0.f, 0.f, 0.f);
    LGD(0, 0, g0) LGD(1, 0, g1) LGD(2, 0, g2) LGD(3, 0, g3)
    LGD(4, 0, g4) LGD(5, 0, g5) LGD(6, 0, g6) LGD(7, 0, g7)
    LAD(0, 0, 0, a0) LAD(0, 0, 1, a1) LAD(0, 1, 0, a2) LAD(0, 1, 1, a3)
    LAD(0, 2, 0, a4) LAD(0, 2, 1, a5) LAD(0, 3, 0, a6) LAD(0, 3, 1, a7)
    if (t < 128) ev = ejt4[(size_t)(hs * 4 + (t >> 5)) * 256 + (t & 31)];

    for (int s = 0; s < 8; ++s) {
        __syncthreads();  // prior super's LDS reads done
#define SG(k, src)                                                               \
        {                                                                        \
            const int u = t + 256 * (k);                                         \
            char* dstp = (char*)gts + (u >> 9) * 10240 + ((u >> 7) & 3) * 2560 + \
                         ((u >> 2) & 31) * 80 + (u & 3) * 16;                    \
            *(float4*)dstp = src;                                                \
        }
        SG(0, g0) SG(1, g1) SG(2, g2) SG(3, g3)
        SG(4, g4) SG(5, g5) SG(6, g6) SG(7, g7)
#undef SG
        if (t < 128) *(float4*)&ejt[t >> 5][(t & 31) * 4] = ev;
        __syncthreads();  // LDS tile visible

        // ---- prefetch next super-step into named regs (hidden under compute)
        const int sn = (s + 1) & 7;
        float4 ng0, ng1, ng2, ng3, ng4, ng5, ng6, ng7;
        f4v na0, na1, na2, na3, na4, na5, na6, na7;
        float4 nev = make_float4(0.f, 0.f, 0.f, 0.f);
        LGD(0, sn, ng0) LGD(1, sn, ng1) LGD(2, sn, ng2) LGD(3, sn, ng3)
        LGD(4, sn, ng4) LGD(5, sn, ng5) LGD(6, sn, ng6) LGD(7, sn, ng7)
        LAD(sn, 0, 0, na0) LAD(sn, 0, 1, na1) LAD(sn, 1, 0, na2) LAD(sn, 1, 1, na3)
        LAD(sn, 2, 0, na4) LAD(sn, 2, 1, na5) LAD(sn, 3, 0, na6) LAD(sn, 3, 1, na7)
        if (t < 128) nev = ejt4[(size_t)(hs * 4 + (t >> 5)) * 256 + sn * 32 + (t & 31)];

        // ---- compute: 4 j-steps of 32, A built in named regs only
#define LT(lt, aA, aB)                                                            \
        {                                                                         \
            const f4v ej0 = *(const f4v*)&ejt[wave][(lt) * 32 + q * 8];           \
            const f4v ej1 = *(const f4v*)&ejt[wave][(lt) * 32 + q * 8 + 4];       \
            s8v A;                                                                \
            A[0] = bf16rne(aA[0] * __expf(lrelu(ei + ej0[0])));                   \
            A[1] = bf16rne(aA[1] * __expf(lrelu(ei + ej0[1])));                   \
            A[2] = bf16rne(aA[2] * __expf(lrelu(ei + ej0[2])));                   \
            A[3] = bf16rne(aA[3] * __expf(lrelu(ei + ej0[3])));                   \
            A[4] = bf16rne(aB[0] * __expf(lrelu(ei + ej1[0])));                   \
            A[5] = bf16rne(aB[1] * __expf(lrelu(ei + ej1[1])));                   \
            A[6] = bf16rne(aB[2] * __expf(lrelu(ei + ej1[2])));                   \
            A[7] = bf16rne(aB[3] * __expf(lrelu(ei + ej1[3])));                   \
            const s8v B0 = *(const s8v*)&gts[wave][lt][m][q * 8];                 \
            const s8v B1 = *(const s8v*)&gts[wave][lt][m + 16][q * 8];            \
            acc0 = __builtin_amdgcn_mfma_f32_16x16x32_bf16(A, B0, acc0, 0, 0, 0); \
            acc1 = __builtin_amdgcn_mfma_f32_16x16x32_bf16(A, B1, acc1, 0, 0, 0); \
        }
        LT(0, a0, a1) LT(1, a2, a3) LT(2, a4, a5) LT(3, a6, a7)
#undef LT

        // ---- rotate (vmcnt waits land here, after compute)
        g0 = ng0; g1 = ng1; g2 = ng2; g3 = ng3;
        g4 = ng4; g5 = ng5; g6 = ng6; g7 = ng7;
        a0 = na0; a1 = na1; a2 = na2; a3 = na3;
        a4 = na4; a5 = na5; a6 = na6; a7 = na7;
        ev = nev;
    }
#undef LGD
#undef LAD

    // ---- epilogue: C layout col=lane&15, row=quad*4+reg
    float* op = out + (size_t)(b * NN + i0) * 256;
#pragma unroll
    for (int r = 0; r < 4; ++r) {
        const int row = q * 4 + r;
        op[(size_t)row * 256 + h * 32 + m] = acc0[r];
        op[(size_t)row * 256 + h * 32 + 16 + m] = acc1[r];
    }
}

// ---------------------------------------------------------------------------
extern "C" void kernel_launch(void* const* d_in, const int* in_sizes, int n_in,
                              void* d_out, int out_size, void* d_ws, size_t ws_size,
                              hipStream_t stream) {
    const float* h      = (const float*)d_in[0];  // [4,1024,256]
    const float* adj    = (const float*)d_in[1];  // [4,1024,1024,1]
    const float* W      = (const float*)d_in[2];  // [256,256]
    const float* attn_w = (const float*)d_in[3];  // [64]
    float* out = (float*)d_out;                   // [4,1024,256]

    float* ws = (float*)d_ws;
    float* g    = ws;                    // 1,048,576 f
    float* e_i  = g + NROW * 256;        // 32,768 f
    float* e_j  = e_i + NROW * 8;        // 32,768 f
    float* e_jt = e_j + NROW * 8;        // 32,768 f  [b][h][n]
    float* ps   = e_jt + NROW * 8;       // 262,144 f
    short* Gt   = (short*)(ps + 8 * NROW * 8);  // 2,097,152 shorts (4MB)

    k_gemm_ei<<<NROW / 8, 256, 0, stream>>>(h, W, attn_w, g, e_i, e_j, e_jt);
    k_s<<<512, 256, 0, stream>>>(adj, e_i, e_j, ps);
    k_prep<<<256, 256, 0, stream>>>(ps, g, Gt);
    k_out_mfma<<<512, 256, 0, stream>>>(adj, Gt, e_i, e_jt, out);
}